// Round 7
// baseline (662.297 us; speedup 1.0000x reference)
//
#include <hip/hip_runtime.h>
#include <hip/hip_bf16.h>
#include <math.h>

#define NN 50000
#define NE 800000
#define FE 16
#define CC 64
#define NG 512
#define NCLS 10
#define NCONV 7
#define SCAN_B 49  // ceil(NN/1024)

typedef float v2f __attribute__((ext_vector_type(2)));

struct MlpP { const float* w1; const float* b1; const float* w2; const float* b2; };
struct MlpAll { MlpP p[NCONV]; };

// ---- CSR build ----
__global__ __launch_bounds__(256) void k_hist(const int* __restrict__ ecol, int* __restrict__ cnt) {
  int e = blockIdx.x * 256 + threadIdx.x;
  if (e < NE) atomicAdd(&cnt[ecol[e]], 1);
}

__global__ __launch_bounds__(1024) void k_scanA(const int* __restrict__ cnt, int* __restrict__ excl,
                                                int* __restrict__ bsum) {
  __shared__ int sc[1024];
  int t = threadIdx.x;
  int i = blockIdx.x * 1024 + t;
  int v = (i < NN) ? cnt[i] : 0;
  sc[t] = v;
  __syncthreads();
  for (int off = 1; off < 1024; off <<= 1) {
    int u = (t >= off) ? sc[t - off] : 0;
    __syncthreads();
    sc[t] += u;
    __syncthreads();
  }
  if (i < NN) excl[i] = sc[t] - v;
  if (t == 1023) bsum[blockIdx.x] = sc[1023];
}

__global__ void k_scanB(const int* __restrict__ bsum, int* __restrict__ boff) {
  int lane = threadIdx.x;  // 64 threads = 1 wave
  int v = (lane < SCAN_B) ? bsum[lane] : 0;
  int own = v;
  for (int off = 1; off < 64; off <<= 1) {
    int u = __shfl_up(v, off);
    if (lane >= off) v += u;
  }
  if (lane < SCAN_B) boff[lane] = v - own;  // exclusive block offset
}

__global__ __launch_bounds__(1024) void k_scanC(const int* __restrict__ excl, const int* __restrict__ boff,
                                                int* __restrict__ cptr, int* __restrict__ cursor) {
  int i = blockIdx.x * 1024 + threadIdx.x;
  if (i < NN) {
    int p = excl[i] + boff[blockIdx.x];
    cptr[i] = p;
    cursor[i] = p;
  }
  if (i == 0) cptr[NN] = NE;
}

// ---- CSR scatter: csrc[p]=src (4B scatter, 3.2MB), pos[e]=p (coalesced) ----
__global__ __launch_bounds__(256) void k_scatter(
    const int* __restrict__ erow, const int* __restrict__ ecol,
    int* __restrict__ cursor, int* __restrict__ csrc, int* __restrict__ pos) {
  int e = blockIdx.x * 256 + threadIdx.x;
  if (e >= NE) return;
  int c = ecol[e];
  int p = atomicAdd(&cursor[c], 1);
  csrc[p] = erow[e];
  pos[e] = p;
}

// ---- all-7 edge MLPs, FOUR edges per thread as 2x v2f (amortize scalar weight stream) ----
__global__ __launch_bounds__(256) void k_mlp(
    const int* __restrict__ pos, const float* __restrict__ ea,
    float* __restrict__ wcsr8, MlpAll mw) {
  int ep = blockIdx.x * 256 + threadIdx.x;
  if (ep >= NE / 4) return;
  int e0 = ep * 4;
  const float4* ea4 = reinterpret_cast<const float4*>(ea + (size_t)e0 * 16);
  float4 A0 = ea4[0],  A1 = ea4[1],  A2 = ea4[2],  A3 = ea4[3];   // edge 0
  float4 B0 = ea4[4],  B1 = ea4[5],  B2 = ea4[6],  B3 = ea4[7];   // edge 1
  float4 C0 = ea4[8],  C1 = ea4[9],  C2 = ea4[10], C3 = ea4[11];  // edge 2
  float4 D0 = ea4[12], D1 = ea4[13], D2 = ea4[14], D3 = ea4[15];  // edge 3
  v2f aA[16], aB[16];
  aA[0]  = (v2f){A0.x, B0.x}; aA[1]  = (v2f){A0.y, B0.y}; aA[2]  = (v2f){A0.z, B0.z}; aA[3]  = (v2f){A0.w, B0.w};
  aA[4]  = (v2f){A1.x, B1.x}; aA[5]  = (v2f){A1.y, B1.y}; aA[6]  = (v2f){A1.z, B1.z}; aA[7]  = (v2f){A1.w, B1.w};
  aA[8]  = (v2f){A2.x, B2.x}; aA[9]  = (v2f){A2.y, B2.y}; aA[10] = (v2f){A2.z, B2.z}; aA[11] = (v2f){A2.w, B2.w};
  aA[12] = (v2f){A3.x, B3.x}; aA[13] = (v2f){A3.y, B3.y}; aA[14] = (v2f){A3.z, B3.z}; aA[15] = (v2f){A3.w, B3.w};
  aB[0]  = (v2f){C0.x, D0.x}; aB[1]  = (v2f){C0.y, D0.y}; aB[2]  = (v2f){C0.z, D0.z}; aB[3]  = (v2f){C0.w, D0.w};
  aB[4]  = (v2f){C1.x, D1.x}; aB[5]  = (v2f){C1.y, D1.y}; aB[6]  = (v2f){C1.z, D1.z}; aB[7]  = (v2f){C1.w, D1.w};
  aB[8]  = (v2f){C2.x, D2.x}; aB[9]  = (v2f){C2.y, D2.y}; aB[10] = (v2f){C2.z, D2.z}; aB[11] = (v2f){C2.w, D2.w};
  aB[12] = (v2f){C3.x, D3.x}; aB[13] = (v2f){C3.y, D3.y}; aB[14] = (v2f){C3.z, D3.z}; aB[15] = (v2f){C3.w, D3.w};
  int4 pp = *reinterpret_cast<const int4*>(pos + e0);
  float wv0[NCONV], wv1[NCONV], wv2[NCONV], wv3[NCONV];
  #pragma unroll
  for (int j = 0; j < NCONV; ++j) {
    const float* w1 = mw.p[j].w1;
    const float* b1 = mw.p[j].b1;
    const float* w2 = mw.p[j].w2;
    float b2v = mw.p[j].b2[0];
    v2f zA = {b2v, b2v}, zB = {b2v, b2v};
    #pragma unroll
    for (int k = 0; k < 16; ++k) {
      float bk = b1[k];
      float wk = w2[k];
      v2f hA = {bk, bk}, hB = {bk, bk};
      #pragma unroll
      for (int m = 0; m < 16; ++m) {
        float wm = w1[k * 16 + m];
        hA += aA[m] * wm;
        hB += aB[m] * wm;
      }
      hA.x = hA.x > 0.f ? hA.x : 0.f;
      hA.y = hA.y > 0.f ? hA.y : 0.f;
      hB.x = hB.x > 0.f ? hB.x : 0.f;
      hB.y = hB.y > 0.f ? hB.y : 0.f;
      zA += hA * wk;
      zB += hB * wk;
    }
    wv0[j] = 1.f / (1.f + __expf(-zA.x));
    wv1[j] = 1.f / (1.f + __expf(-zA.y));
    wv2[j] = 1.f / (1.f + __expf(-zB.x));
    wv3[j] = 1.f / (1.f + __expf(-zB.y));
  }
  float4* d0 = reinterpret_cast<float4*>(wcsr8 + (size_t)pp.x * 8);
  d0[0] = make_float4(wv0[0], wv0[1], wv0[2], wv0[3]);
  d0[1] = make_float4(wv0[4], wv0[5], wv0[6], 0.f);
  float4* d1 = reinterpret_cast<float4*>(wcsr8 + (size_t)pp.y * 8);
  d1[0] = make_float4(wv1[0], wv1[1], wv1[2], wv1[3]);
  d1[1] = make_float4(wv1[4], wv1[5], wv1[6], 0.f);
  float4* d2 = reinterpret_cast<float4*>(wcsr8 + (size_t)pp.z * 8);
  d2[0] = make_float4(wv2[0], wv2[1], wv2[2], wv2[3]);
  d2[1] = make_float4(wv2[4], wv2[5], wv2[6], 0.f);
  float4* d3 = reinterpret_cast<float4*>(wcsr8 + (size_t)pp.w * 8);
  d3[0] = make_float4(wv3[0], wv3[1], wv3[2], wv3[3]);
  d3[1] = make_float4(wv3[4], wv3[5], wv3[6], 0.f);
}

// ---- repack wcsr8 chunks -> 7 dense CSR-order planes (all coalesced) ----
__global__ __launch_bounds__(256) void k_repack(const float* __restrict__ wcsr8, float* __restrict__ wpl) {
  int p = blockIdx.x * 256 + threadIdx.x;
  if (p >= NE) return;
  const float4* q = reinterpret_cast<const float4*>(wcsr8 + (size_t)p * 8);
  float4 a = q[0], b = q[1];
  wpl[0 * (size_t)NE + p] = a.x;
  wpl[1 * (size_t)NE + p] = a.y;
  wpl[2 * (size_t)NE + p] = a.z;
  wpl[3 * (size_t)NE + p] = a.w;
  wpl[4 * (size_t)NE + p] = b.x;
  wpl[5 * (size_t)NE + p] = b.y;
  wpl[6 * (size_t)NE + p] = b.z;
}

// ---- deg per (node, conv) via CSR gather-sum; fused rsqrt -> dis ----
__global__ __launch_bounds__(256) void k_deg(const float* __restrict__ wcsr8,
                                             const int* __restrict__ cptr,
                                             float* __restrict__ dis) {
  int n = blockIdx.x * 256 + threadIdx.x;
  if (n >= NN) return;
  int lo = cptr[n], hi = cptr[n + 1];
  float s0=0,s1=0,s2=0,s3=0,s4=0,s5=0,s6=0;
  for (int k = lo; k < hi; ++k) {
    const float4* q = reinterpret_cast<const float4*>(wcsr8 + (size_t)k * 8);
    float4 a = q[0], b = q[1];
    s0+=a.x; s1+=a.y; s2+=a.z; s3+=a.w; s4+=b.x; s5+=b.y; s6+=b.z;
  }
  dis[0*NN+n]=rsqrtf(s0+1.f); dis[1*NN+n]=rsqrtf(s1+1.f); dis[2*NN+n]=rsqrtf(s2+1.f);
  dis[3*NN+n]=rsqrtf(s3+1.f); dis[4*NN+n]=rsqrtf(s4+1.f); dis[5*NN+n]=rsqrtf(s5+1.f);
  dis[6*NN+n]=rsqrtf(s6+1.f);
}

// transpose the 7 node-linear weights: lwT[j][ci][co] = lw_j[co][ci]
__global__ __launch_bounds__(256) void k_lwt(const float* __restrict__ c1, const float* __restrict__ h1,
                                             const float* __restrict__ h2, float* __restrict__ lwT) {
  int id = blockIdx.x * 256 + threadIdx.x;
  if (id >= NCONV * CC * CC) return;
  int j = id >> 12;
  int r = id & 4095;
  int co = r >> 6, ci = r & 63;
  const float* src = (j == 0) ? c1 : (j <= 3 ? h1 + (j - 1) * 4096 : h2 + (j - 4) * 4096);
  lwT[j * 4096 + ci * 64 + co] = src[co * 64 + ci];
}

// ---- BatchNorm stats: S and SS per channel ----
__global__ __launch_bounds__(256) void k_bnstat(const float* __restrict__ src, float* __restrict__ accum) {
  __shared__ float sS[256], sQ[256];
  int t = threadIdx.x;
  int c = t & 63, rg = t >> 6;
  int base = blockIdx.x * 196;
  float S = 0.f, Q = 0.f;
  for (int rr = rg; rr < 196; rr += 4) {
    int r = base + rr;
    if (r < NN) { float v = src[r * 64 + c]; S += v; Q += v * v; }
  }
  sS[t] = S; sQ[t] = Q;
  __syncthreads();
  if (t < 128) { sS[t] += sS[t + 128]; sQ[t] += sQ[t + 128]; }
  __syncthreads();
  if (t < 64) {
    atomicAdd(&accum[c], sS[t] + sS[t + 64]);
    atomicAdd(&accum[64 + c], sQ[t] + sQ[t + 64]);
  }
}

// ---- fused (BN+ReLU)? -> GEMM -> *dis : dst = f(src) @ lwT * dis[n] ----
__global__ __launch_bounds__(256) void k_gemm(const float* __restrict__ src, const float* __restrict__ lwT,
                                              const float* __restrict__ accum, const float* __restrict__ dis,
                                              float* __restrict__ dst, int useBN) {
  __shared__ float xs[64 * 65];
  int t = threadIdx.x;
  int rows0 = blockIdx.x * 64;
  for (int i = 0; i < 4; ++i) {
    int f = t + i * 256;            // float4 index in [0,1024)
    int r = f >> 4, c4 = (f & 15) * 4;
    int row = rows0 + r;
    float4 v = make_float4(0.f, 0.f, 0.f, 0.f);
    if (row < NN) v = *reinterpret_cast<const float4*>(src + (size_t)row * 64 + c4);
    if (useBN) {
      float4 S = *reinterpret_cast<const float4*>(accum + c4);
      float4 Q = *reinterpret_cast<const float4*>(accum + 64 + c4);
      float mu, var, rs;
      mu = S.x * (1.0f/NN); var = Q.x*(1.0f/NN)-mu*mu; var = var<0.f?0.f:var; rs = rsqrtf(var+1e-5f);
      v.x = (v.x-mu)*rs; v.x = v.x>0.f?v.x:0.f;
      mu = S.y * (1.0f/NN); var = Q.y*(1.0f/NN)-mu*mu; var = var<0.f?0.f:var; rs = rsqrtf(var+1e-5f);
      v.y = (v.y-mu)*rs; v.y = v.y>0.f?v.y:0.f;
      mu = S.z * (1.0f/NN); var = Q.z*(1.0f/NN)-mu*mu; var = var<0.f?0.f:var; rs = rsqrtf(var+1e-5f);
      v.z = (v.z-mu)*rs; v.z = v.z>0.f?v.z:0.f;
      mu = S.w * (1.0f/NN); var = Q.w*(1.0f/NN)-mu*mu; var = var<0.f?0.f:var; rs = rsqrtf(var+1e-5f);
      v.w = (v.w-mu)*rs; v.w = v.w>0.f?v.w:0.f;
    }
    xs[r * 65 + c4 + 0] = v.x;
    xs[r * 65 + c4 + 1] = v.y;
    xs[r * 65 + c4 + 2] = v.z;
    xs[r * 65 + c4 + 3] = v.w;
  }
  __syncthreads();
  int lane = t & 63;
  int cobase = __builtin_amdgcn_readfirstlane((t >> 6) << 4);  // wave-uniform -> scalar weight loads
  float acc[16];
  #pragma unroll
  for (int u = 0; u < 16; ++u) acc[u] = 0.f;
  #pragma unroll 8
  for (int ci = 0; ci < 64; ++ci) {
    float xv = xs[lane * 65 + ci];
    const float* wrow = lwT + ci * 64 + cobase;
    #pragma unroll
    for (int u = 0; u < 16; ++u) acc[u] += xv * wrow[u];
  }
  __syncthreads();
  int row = rows0 + lane;
  float d = (row < NN) ? dis[row] : 0.f;
  #pragma unroll
  for (int u = 0; u < 16; ++u) xs[lane * 65 + cobase + u] = acc[u] * d;
  __syncthreads();
  for (int i = 0; i < 4; ++i) {
    int f = t + i * 256;
    int r = f >> 4, c4 = (f & 15) * 4;
    int orow = rows0 + r;
    if (orow < NN) {
      float4 v = make_float4(xs[r*65+c4], xs[r*65+c4+1], xs[r*65+c4+2], xs[r*65+c4+3]);
      *reinterpret_cast<float4*>(dst + (size_t)orow * 64 + c4) = v;
    }
  }
}

// ---- aggregation v2: wave per node; lanes = 4 edges x 16 channel-quarters ----
// 4 coalesced row-gathers in flight per instr; shfl_xor reduce over edge dim.
// wstride: 1 (dense plane) or 8 (wcsr8 fallback)
// mode 0: out = v ; mode 1: X1 = v + skipA ; mode 2: relu(v+skipA+skipX1) -> atomicMax pool
__global__ __launch_bounds__(256) void k_agg(const float* __restrict__ T, const float* __restrict__ wj,
                                             const int* __restrict__ csrc, const int* __restrict__ cptr,
                                             const float* __restrict__ dis, float* __restrict__ out,
                                             const float* __restrict__ skipA, const float* __restrict__ skipX1,
                                             float* __restrict__ outX1, const int* __restrict__ batch,
                                             int* __restrict__ poolI, int wstride, int mode) {
  int t = threadIdx.x;
  int n = blockIdx.x * 4 + (t >> 6);
  if (n >= NN) return;
  int lane = t & 63;
  int e4 = lane >> 4;     // edge slot 0..3
  int cq = lane & 15;     // channel quarter 0..15
  int lo = cptr[n], hi = cptr[n + 1];

  // self loop: only edge-slot 0 carries it
  float4 tn = reinterpret_cast<const float4*>(T + (size_t)n * 64)[cq];
  float4 acc;
  acc.x = e4 == 0 ? tn.x : 0.f;
  acc.y = e4 == 0 ? tn.y : 0.f;
  acc.z = e4 == 0 ? tn.z : 0.f;
  acc.w = e4 == 0 ? tn.w : 0.f;

  // software-pipelined: prefetch (s,w) for the group, gather rows, repeat
  int base = lo;
  int k = base + e4;
  bool val = k < hi;
  int s = val ? csrc[k] : n;
  float w = val ? wj[(size_t)k * wstride] : 0.f;
  while (base < hi) {           // wave-uniform condition
    int curs = s;
    float curw = w;
    base += 4;
    k = base + e4;
    bool v2 = k < hi;
    s = v2 ? csrc[k] : n;
    w = v2 ? wj[(size_t)k * wstride] : 0.f;
    float4 q = reinterpret_cast<const float4*>(T + (size_t)curs * 64)[cq];
    acc.x += curw * q.x;
    acc.y += curw * q.y;
    acc.z += curw * q.z;
    acc.w += curw * q.w;
  }

  // reduce over edge slots (lanes stride 16, then 32)
  acc.x += __shfl_xor(acc.x, 16); acc.y += __shfl_xor(acc.y, 16);
  acc.z += __shfl_xor(acc.z, 16); acc.w += __shfl_xor(acc.w, 16);
  acc.x += __shfl_xor(acc.x, 32); acc.y += __shfl_xor(acc.y, 32);
  acc.z += __shfl_xor(acc.z, 32); acc.w += __shfl_xor(acc.w, 32);

  if (e4 != 0) return;
  float d = dis[n];
  float4 v = make_float4(acc.x * d, acc.y * d, acc.z * d, acc.w * d);
  size_t ridx = (size_t)n * 16 + cq;
  if (mode == 1) {
    float4 a = reinterpret_cast<const float4*>(skipA)[ridx];
    float4 sv = make_float4(v.x + a.x, v.y + a.y, v.z + a.z, v.w + a.w);
    reinterpret_cast<float4*>(outX1)[ridx] = sv;
  } else if (mode == 2) {
    float4 a = reinterpret_cast<const float4*>(skipA)[ridx];
    float4 x1 = reinterpret_cast<const float4*>(skipX1)[ridx];
    float4 sv = make_float4(v.x + a.x + x1.x, v.y + a.y + x1.y, v.z + a.z + x1.z, v.w + a.w + x1.w);
    sv.x = sv.x > 0.f ? sv.x : 0.f;
    sv.y = sv.y > 0.f ? sv.y : 0.f;
    sv.z = sv.z > 0.f ? sv.z : 0.f;
    sv.w = sv.w > 0.f ? sv.w : 0.f;
    int g = batch[n];
    int* pb = poolI + (size_t)g * 64 + cq * 4;
    atomicMax(pb + 0, __float_as_int(sv.x));
    atomicMax(pb + 1, __float_as_int(sv.y));
    atomicMax(pb + 2, __float_as_int(sv.z));
    atomicMax(pb + 3, __float_as_int(sv.w));
  } else {
    reinterpret_cast<float4*>(out)[ridx] = v;
  }
}

__global__ __launch_bounds__(256) void k_cls(const float* __restrict__ pooled, const float* __restrict__ lw,
                                             const float* __restrict__ lb, float* __restrict__ out) {
  int id = blockIdx.x * 256 + threadIdx.x;
  if (id >= NG * NCLS) return;
  int g = id / NCLS, k = id % NCLS;
  float acc = lb[k];
  #pragma unroll 8
  for (int c = 0; c < 64; ++c) acc += pooled[g * 64 + c] * lw[k * 64 + c];
  out[id] = acc;
}

extern "C" void kernel_launch(void* const* d_in, const int* in_sizes, int n_in,
                              void* d_out, int out_size, void* d_ws, size_t ws_size,
                              hipStream_t stream) {
  (void)in_sizes; (void)n_in; (void)out_size;
  const float* x     = (const float*)d_in[0];
  const int*   ei    = (const int*)d_in[1];
  const int*   batch = (const int*)d_in[2];
  // d_in[3] = dropout (0) -- unused
  const float* ea    = (const float*)d_in[4];
  const float* c1_lw = (const float*)d_in[5];
  const float* c1_w1 = (const float*)d_in[6];
  const float* c1_b1 = (const float*)d_in[7];
  const float* c1_w2 = (const float*)d_in[8];
  const float* c1_b2 = (const float*)d_in[9];
  const float* h1_lw = (const float*)d_in[10];
  const float* h1_w1 = (const float*)d_in[11];
  const float* h1_b1 = (const float*)d_in[12];
  const float* h1_w2 = (const float*)d_in[13];
  const float* h1_b2 = (const float*)d_in[14];
  const float* h2_lw = (const float*)d_in[15];
  const float* h2_w1 = (const float*)d_in[16];
  const float* h2_b1 = (const float*)d_in[17];
  const float* h2_w2 = (const float*)d_in[18];
  const float* h2_b2 = (const float*)d_in[19];
  const float* lin_w = (const float*)d_in[20];
  const float* lin_b = (const float*)d_in[21];
  float* out = (float*)d_out;

  char* base = (char*)d_ws;
  size_t off = 0;
  auto alloc = [&](size_t bytes) -> size_t {
    size_t o = off;
    off = (off + bytes + 255) & ~(size_t)255;
    return o;
  };
  size_t o_wcsr8  = alloc((size_t)NE * 8 * 4);        // 25.6MB, CSR order, 8 floats/edge
  size_t o_csrc   = alloc((size_t)NE * 4);
  size_t o_pos    = alloc((size_t)NE * 4);
  size_t o_cptr   = alloc((size_t)(NN + 1) * 4);
  size_t o_excl   = alloc((size_t)NN * 4);
  size_t o_bsum   = alloc((size_t)64 * 4);
  size_t o_boff   = alloc((size_t)64 * 4);
  size_t o_cnt    = alloc((size_t)NN * 4);            // zeroed region starts here (cnt -> cursor)
  size_t o_accum  = alloc((size_t)6 * 128 * 4);       // zeroed region ends after this
  size_t o_dis    = alloc((size_t)NCONV * NN * 4);
  size_t o_lwt    = alloc((size_t)NCONV * 4096 * 4);
  size_t o_T      = alloc((size_t)NN * 64 * 4);
  size_t o_A      = alloc((size_t)NN * 64 * 4);
  size_t o_B      = alloc((size_t)NN * 64 * 4);
  size_t o_X1     = alloc((size_t)NN * 64 * 4);
  size_t o_pool   = alloc((size_t)NG * 64 * 4);
  size_t o_wpl    = alloc((size_t)NCONV * NE * 4);    // 22.4MB dense planes -- LAST, gated on ws_size
  bool use_planes = (off <= ws_size);

  float* wcsr8  = (float*)(base + o_wcsr8);
  int*   csrc   = (int*)(base + o_csrc);
  int*   pos    = (int*)(base + o_pos);
  int*   cptr   = (int*)(base + o_cptr);
  int*   excl   = (int*)(base + o_excl);
  int*   bsum   = (int*)(base + o_bsum);
  int*   boff   = (int*)(base + o_boff);
  int*   cnt    = (int*)(base + o_cnt);   // doubles as cursor after scanC
  float* accum  = (float*)(base + o_accum);
  float* dis    = (float*)(base + o_dis);
  float* lwt    = (float*)(base + o_lwt);
  float* T      = (float*)(base + o_T);
  float* A      = (float*)(base + o_A);
  float* B      = (float*)(base + o_B);
  float* X1     = (float*)(base + o_X1);
  float* pooled = (float*)(base + o_pool);
  float* wpl    = (float*)(base + o_wpl);

  // zero: cnt + accum (contiguous), and pooled (atomicMax target; relu values >= 0)
  hipMemsetAsync(base + o_cnt, 0, o_dis - o_cnt, stream);
  hipMemsetAsync(base + o_pool, 0, (size_t)NG * 64 * 4, stream);

  const int* erow = ei;
  const int* ecol = ei + NE;

  k_hist<<<(NE + 255) / 256, 256, 0, stream>>>(ecol, cnt);
  k_scanA<<<SCAN_B, 1024, 0, stream>>>(cnt, excl, bsum);
  k_scanB<<<1, 64, 0, stream>>>(bsum, boff);
  k_scanC<<<SCAN_B, 1024, 0, stream>>>(excl, boff, cptr, cnt);
  k_scatter<<<(NE + 255) / 256, 256, 0, stream>>>(erow, ecol, cnt, csrc, pos);

  MlpAll mw;
  mw.p[0] = {c1_w1, c1_b1, c1_w2, c1_b2};
  for (int i = 0; i < 3; ++i) {
    mw.p[1 + i] = {h1_w1 + i * 256, h1_b1 + i * 16, h1_w2 + i * 16, h1_b2 + i};
    mw.p[4 + i] = {h2_w1 + i * 256, h2_b1 + i * 16, h2_w2 + i * 16, h2_b2 + i};
  }
  k_mlp<<<(NE / 4 + 255) / 256, 256, 0, stream>>>(pos, ea, wcsr8, mw);
  if (use_planes) k_repack<<<(NE + 255) / 256, 256, 0, stream>>>(wcsr8, wpl);
  k_deg<<<(NN + 255) / 256, 256, 0, stream>>>(wcsr8, cptr, dis);
  k_lwt<<<(NCONV * 4096) / 256, 256, 0, stream>>>(c1_lw, h1_lw, h2_lw, lwt);

  const int GB = (NN + 63) / 64;  // 782
  const int AB = (NN + 3) / 4;    // 12500
  auto wbase = [&](int j) -> const float* {
    return use_planes ? (wpl + (size_t)j * NE) : (wcsr8 + j);
  };
  const int WS = use_planes ? 1 : 8;

  // conv1 -> A (= x0)
  k_gemm<<<GB, 256, 0, stream>>>(x, lwt, nullptr, dis, T, 0);
  k_agg<<<AB, 256, 0, stream>>>(T, wbase(0), csrc, cptr, dis, A,
                                nullptr, nullptr, nullptr, nullptr, nullptr, WS, 0);

  // hidden loop 1: x = conv(relu(BN(x))); after i==2 fuse x1 = x + x0 -> X1 only
  for (int i = 0; i < 3; ++i) {
    const float* src = (i == 0) ? A : B;
    k_bnstat<<<256, 256, 0, stream>>>(src, accum + i * 128);
    k_gemm<<<GB, 256, 0, stream>>>(src, lwt + (1 + i) * 4096, accum + i * 128,
                                   dis + (size_t)(1 + i) * NN, T, 1);
    int mode = (i == 2) ? 1 : 0;
    k_agg<<<AB, 256, 0, stream>>>(T, wbase(1 + i), csrc, cptr,
                                  dis + (size_t)(1 + i) * NN, B, A, nullptr, X1,
                                  nullptr, nullptr, WS, mode);
  }
  // hidden loop 2 (input = X1); after i==2 fuse x2=relu(x+x0+x1) + max-pool via atomics
  for (int i = 0; i < 3; ++i) {
    const float* src = (i == 0) ? X1 : B;
    k_bnstat<<<256, 256, 0, stream>>>(src, accum + (3 + i) * 128);
    k_gemm<<<GB, 256, 0, stream>>>(src, lwt + (4 + i) * 4096, accum + (3 + i) * 128,
                                   dis + (size_t)(4 + i) * NN, T, 1);
    int mode = (i == 2) ? 2 : 0;
    k_agg<<<AB, 256, 0, stream>>>(T, wbase(4 + i), csrc, cptr,
                                  dis + (size_t)(4 + i) * NN, B, A, X1, nullptr,
                                  batch, (int*)pooled, WS, mode);
  }

  k_cls<<<(NG * NCLS + 255) / 256, 256, 0, stream>>>(pooled, lin_w, lin_b, out);
}

// Round 8
// 599.040 us; speedup vs baseline: 1.1056x; 1.1056x over previous
//
#include <hip/hip_runtime.h>
#include <hip/hip_bf16.h>
#include <hip/hip_fp16.h>
#include <math.h>

#define NN 50000
#define NE 800000
#define FE 16
#define CC 64
#define NG 512
#define NCLS 10
#define NCONV 7
#define SCAN_B 49  // ceil(NN/1024)

typedef float v2f __attribute__((ext_vector_type(2)));

struct MlpP { const float* w1; const float* b1; const float* w2; const float* b2; };
struct MlpAll { MlpP p[NCONV]; };

__device__ __forceinline__ float4 ld_half4(const __half* p) {
  uint2 r = *reinterpret_cast<const uint2*>(p);
  __half2 a = *reinterpret_cast<const __half2*>(&r.x);
  __half2 b = *reinterpret_cast<const __half2*>(&r.y);
  float2 fa = __half22float2(a);
  float2 fb = __half22float2(b);
  return make_float4(fa.x, fa.y, fb.x, fb.y);
}

// ---- CSR build ----
__global__ __launch_bounds__(256) void k_hist(const int* __restrict__ ecol, int* __restrict__ cnt) {
  int e = blockIdx.x * 256 + threadIdx.x;
  if (e < NE) atomicAdd(&cnt[ecol[e]], 1);
}

__global__ __launch_bounds__(1024) void k_scanA(const int* __restrict__ cnt, int* __restrict__ excl,
                                                int* __restrict__ bsum) {
  __shared__ int sc[1024];
  int t = threadIdx.x;
  int i = blockIdx.x * 1024 + t;
  int v = (i < NN) ? cnt[i] : 0;
  sc[t] = v;
  __syncthreads();
  for (int off = 1; off < 1024; off <<= 1) {
    int u = (t >= off) ? sc[t - off] : 0;
    __syncthreads();
    sc[t] += u;
    __syncthreads();
  }
  if (i < NN) excl[i] = sc[t] - v;
  if (t == 1023) bsum[blockIdx.x] = sc[1023];
}

__global__ void k_scanB(const int* __restrict__ bsum, int* __restrict__ boff) {
  int lane = threadIdx.x;  // 64 threads = 1 wave
  int v = (lane < SCAN_B) ? bsum[lane] : 0;
  int own = v;
  for (int off = 1; off < 64; off <<= 1) {
    int u = __shfl_up(v, off);
    if (lane >= off) v += u;
  }
  if (lane < SCAN_B) boff[lane] = v - own;  // exclusive block offset
}

__global__ __launch_bounds__(1024) void k_scanC(const int* __restrict__ excl, const int* __restrict__ boff,
                                                int* __restrict__ cptr, int* __restrict__ cursor) {
  int i = blockIdx.x * 1024 + threadIdx.x;
  if (i < NN) {
    int p = excl[i] + boff[blockIdx.x];
    cptr[i] = p;
    cursor[i] = p;
  }
  if (i == 0) cptr[NN] = NE;
}

// ---- CSR scatter: csrc[p]=src (4B scatter, 3.2MB), pos[e]=p (coalesced) ----
__global__ __launch_bounds__(256) void k_scatter(
    const int* __restrict__ erow, const int* __restrict__ ecol,
    int* __restrict__ cursor, int* __restrict__ csrc, int* __restrict__ pos) {
  int e = blockIdx.x * 256 + threadIdx.x;
  if (e >= NE) return;
  int c = ecol[e];
  int p = atomicAdd(&cursor[c], 1);
  csrc[p] = erow[e];
  pos[e] = p;
}

// ---- all-7 edge MLPs, FOUR edges per thread as 2x v2f (amortize scalar weight stream) ----
__global__ __launch_bounds__(256) void k_mlp(
    const int* __restrict__ pos, const float* __restrict__ ea,
    float* __restrict__ wcsr8, MlpAll mw) {
  int ep = blockIdx.x * 256 + threadIdx.x;
  if (ep >= NE / 4) return;
  int e0 = ep * 4;
  const float4* ea4 = reinterpret_cast<const float4*>(ea + (size_t)e0 * 16);
  float4 A0 = ea4[0],  A1 = ea4[1],  A2 = ea4[2],  A3 = ea4[3];   // edge 0
  float4 B0 = ea4[4],  B1 = ea4[5],  B2 = ea4[6],  B3 = ea4[7];   // edge 1
  float4 C0 = ea4[8],  C1 = ea4[9],  C2 = ea4[10], C3 = ea4[11];  // edge 2
  float4 D0 = ea4[12], D1 = ea4[13], D2 = ea4[14], D3 = ea4[15];  // edge 3
  v2f aA[16], aB[16];
  aA[0]  = (v2f){A0.x, B0.x}; aA[1]  = (v2f){A0.y, B0.y}; aA[2]  = (v2f){A0.z, B0.z}; aA[3]  = (v2f){A0.w, B0.w};
  aA[4]  = (v2f){A1.x, B1.x}; aA[5]  = (v2f){A1.y, B1.y}; aA[6]  = (v2f){A1.z, B1.z}; aA[7]  = (v2f){A1.w, B1.w};
  aA[8]  = (v2f){A2.x, B2.x}; aA[9]  = (v2f){A2.y, B2.y}; aA[10] = (v2f){A2.z, B2.z}; aA[11] = (v2f){A2.w, B2.w};
  aA[12] = (v2f){A3.x, B3.x}; aA[13] = (v2f){A3.y, B3.y}; aA[14] = (v2f){A3.z, B3.z}; aA[15] = (v2f){A3.w, B3.w};
  aB[0]  = (v2f){C0.x, D0.x}; aB[1]  = (v2f){C0.y, D0.y}; aB[2]  = (v2f){C0.z, D0.z}; aB[3]  = (v2f){C0.w, D0.w};
  aB[4]  = (v2f){C1.x, D1.x}; aB[5]  = (v2f){C1.y, D1.y}; aB[6]  = (v2f){C1.z, D1.z}; aB[7]  = (v2f){C1.w, D1.w};
  aB[8]  = (v2f){C2.x, D2.x}; aB[9]  = (v2f){C2.y, D2.y}; aB[10] = (v2f){C2.z, D2.z}; aB[11] = (v2f){C2.w, D2.w};
  aB[12] = (v2f){C3.x, D3.x}; aB[13] = (v2f){C3.y, D3.y}; aB[14] = (v2f){C3.z, D3.z}; aB[15] = (v2f){C3.w, D3.w};
  int4 pp = *reinterpret_cast<const int4*>(pos + e0);
  float wv0[NCONV], wv1[NCONV], wv2[NCONV], wv3[NCONV];
  #pragma unroll
  for (int j = 0; j < NCONV; ++j) {
    const float* w1 = mw.p[j].w1;
    const float* b1 = mw.p[j].b1;
    const float* w2 = mw.p[j].w2;
    float b2v = mw.p[j].b2[0];
    v2f zA = {b2v, b2v}, zB = {b2v, b2v};
    #pragma unroll
    for (int k = 0; k < 16; ++k) {
      float bk = b1[k];
      float wk = w2[k];
      v2f hA = {bk, bk}, hB = {bk, bk};
      #pragma unroll
      for (int m = 0; m < 16; ++m) {
        float wm = w1[k * 16 + m];
        hA += aA[m] * wm;
        hB += aB[m] * wm;
      }
      hA.x = hA.x > 0.f ? hA.x : 0.f;
      hA.y = hA.y > 0.f ? hA.y : 0.f;
      hB.x = hB.x > 0.f ? hB.x : 0.f;
      hB.y = hB.y > 0.f ? hB.y : 0.f;
      zA += hA * wk;
      zB += hB * wk;
    }
    wv0[j] = 1.f / (1.f + __expf(-zA.x));
    wv1[j] = 1.f / (1.f + __expf(-zA.y));
    wv2[j] = 1.f / (1.f + __expf(-zB.x));
    wv3[j] = 1.f / (1.f + __expf(-zB.y));
  }
  float4* d0 = reinterpret_cast<float4*>(wcsr8 + (size_t)pp.x * 8);
  d0[0] = make_float4(wv0[0], wv0[1], wv0[2], wv0[3]);
  d0[1] = make_float4(wv0[4], wv0[5], wv0[6], 0.f);
  float4* d1 = reinterpret_cast<float4*>(wcsr8 + (size_t)pp.y * 8);
  d1[0] = make_float4(wv1[0], wv1[1], wv1[2], wv1[3]);
  d1[1] = make_float4(wv1[4], wv1[5], wv1[6], 0.f);
  float4* d2 = reinterpret_cast<float4*>(wcsr8 + (size_t)pp.z * 8);
  d2[0] = make_float4(wv2[0], wv2[1], wv2[2], wv2[3]);
  d2[1] = make_float4(wv2[4], wv2[5], wv2[6], 0.f);
  float4* d3 = reinterpret_cast<float4*>(wcsr8 + (size_t)pp.w * 8);
  d3[0] = make_float4(wv3[0], wv3[1], wv3[2], wv3[3]);
  d3[1] = make_float4(wv3[4], wv3[5], wv3[6], 0.f);
}

// ---- repack wcsr8 chunks -> 7 dense CSR-order planes (all coalesced) ----
__global__ __launch_bounds__(256) void k_repack(const float* __restrict__ wcsr8, float* __restrict__ wpl) {
  int p = blockIdx.x * 256 + threadIdx.x;
  if (p >= NE) return;
  const float4* q = reinterpret_cast<const float4*>(wcsr8 + (size_t)p * 8);
  float4 a = q[0], b = q[1];
  wpl[0 * (size_t)NE + p] = a.x;
  wpl[1 * (size_t)NE + p] = a.y;
  wpl[2 * (size_t)NE + p] = a.z;
  wpl[3 * (size_t)NE + p] = a.w;
  wpl[4 * (size_t)NE + p] = b.x;
  wpl[5 * (size_t)NE + p] = b.y;
  wpl[6 * (size_t)NE + p] = b.z;
}

// ---- deg per (node, conv) via CSR gather-sum; fused rsqrt -> dis ----
__global__ __launch_bounds__(256) void k_deg(const float* __restrict__ wcsr8,
                                             const int* __restrict__ cptr,
                                             float* __restrict__ dis) {
  int n = blockIdx.x * 256 + threadIdx.x;
  if (n >= NN) return;
  int lo = cptr[n], hi = cptr[n + 1];
  float s0=0,s1=0,s2=0,s3=0,s4=0,s5=0,s6=0;
  for (int k = lo; k < hi; ++k) {
    const float4* q = reinterpret_cast<const float4*>(wcsr8 + (size_t)k * 8);
    float4 a = q[0], b = q[1];
    s0+=a.x; s1+=a.y; s2+=a.z; s3+=a.w; s4+=b.x; s5+=b.y; s6+=b.z;
  }
  dis[0*NN+n]=rsqrtf(s0+1.f); dis[1*NN+n]=rsqrtf(s1+1.f); dis[2*NN+n]=rsqrtf(s2+1.f);
  dis[3*NN+n]=rsqrtf(s3+1.f); dis[4*NN+n]=rsqrtf(s4+1.f); dis[5*NN+n]=rsqrtf(s5+1.f);
  dis[6*NN+n]=rsqrtf(s6+1.f);
}

// transpose the 7 node-linear weights: lwT[j][ci][co] = lw_j[co][ci]
__global__ __launch_bounds__(256) void k_lwt(const float* __restrict__ c1, const float* __restrict__ h1,
                                             const float* __restrict__ h2, float* __restrict__ lwT) {
  int id = blockIdx.x * 256 + threadIdx.x;
  if (id >= NCONV * CC * CC) return;
  int j = id >> 12;
  int r = id & 4095;
  int co = r >> 6, ci = r & 63;
  const float* src = (j == 0) ? c1 : (j <= 3 ? h1 + (j - 1) * 4096 : h2 + (j - 4) * 4096);
  lwT[j * 4096 + ci * 64 + co] = src[co * 64 + ci];
}

// ---- BatchNorm stats: S and SS per channel ----
__global__ __launch_bounds__(256) void k_bnstat(const float* __restrict__ src, float* __restrict__ accum) {
  __shared__ float sS[256], sQ[256];
  int t = threadIdx.x;
  int c = t & 63, rg = t >> 6;
  int base = blockIdx.x * 196;
  float S = 0.f, Q = 0.f;
  for (int rr = rg; rr < 196; rr += 4) {
    int r = base + rr;
    if (r < NN) { float v = src[r * 64 + c]; S += v; Q += v * v; }
  }
  sS[t] = S; sQ[t] = Q;
  __syncthreads();
  if (t < 128) { sS[t] += sS[t + 128]; sQ[t] += sQ[t + 128]; }
  __syncthreads();
  if (t < 64) {
    atomicAdd(&accum[c], sS[t] + sS[t + 64]);
    atomicAdd(&accum[64 + c], sQ[t] + sQ[t + 64]);
  }
}

// ---- fused (BN+ReLU)? -> GEMM -> *dis -> fp16 : dstH = half(f(src) @ lwT * dis[n]) ----
__global__ __launch_bounds__(256) void k_gemm(const float* __restrict__ src, const float* __restrict__ lwT,
                                              const float* __restrict__ accum, const float* __restrict__ dis,
                                              __half* __restrict__ dstH, int useBN) {
  __shared__ float xs[64 * 65];
  int t = threadIdx.x;
  int rows0 = blockIdx.x * 64;
  for (int i = 0; i < 4; ++i) {
    int f = t + i * 256;            // float4 index in [0,1024)
    int r = f >> 4, c4 = (f & 15) * 4;
    int row = rows0 + r;
    float4 v = make_float4(0.f, 0.f, 0.f, 0.f);
    if (row < NN) v = *reinterpret_cast<const float4*>(src + (size_t)row * 64 + c4);
    if (useBN) {
      float4 S = *reinterpret_cast<const float4*>(accum + c4);
      float4 Q = *reinterpret_cast<const float4*>(accum + 64 + c4);
      float mu, var, rs;
      mu = S.x * (1.0f/NN); var = Q.x*(1.0f/NN)-mu*mu; var = var<0.f?0.f:var; rs = rsqrtf(var+1e-5f);
      v.x = (v.x-mu)*rs; v.x = v.x>0.f?v.x:0.f;
      mu = S.y * (1.0f/NN); var = Q.y*(1.0f/NN)-mu*mu; var = var<0.f?0.f:var; rs = rsqrtf(var+1e-5f);
      v.y = (v.y-mu)*rs; v.y = v.y>0.f?v.y:0.f;
      mu = S.z * (1.0f/NN); var = Q.z*(1.0f/NN)-mu*mu; var = var<0.f?0.f:var; rs = rsqrtf(var+1e-5f);
      v.z = (v.z-mu)*rs; v.z = v.z>0.f?v.z:0.f;
      mu = S.w * (1.0f/NN); var = Q.w*(1.0f/NN)-mu*mu; var = var<0.f?0.f:var; rs = rsqrtf(var+1e-5f);
      v.w = (v.w-mu)*rs; v.w = v.w>0.f?v.w:0.f;
    }
    xs[r * 65 + c4 + 0] = v.x;
    xs[r * 65 + c4 + 1] = v.y;
    xs[r * 65 + c4 + 2] = v.z;
    xs[r * 65 + c4 + 3] = v.w;
  }
  __syncthreads();
  int lane = t & 63;
  int cobase = __builtin_amdgcn_readfirstlane((t >> 6) << 4);  // wave-uniform -> scalar weight loads
  float acc[16];
  #pragma unroll
  for (int u = 0; u < 16; ++u) acc[u] = 0.f;
  #pragma unroll 8
  for (int ci = 0; ci < 64; ++ci) {
    float xv = xs[lane * 65 + ci];
    const float* wrow = lwT + ci * 64 + cobase;
    #pragma unroll
    for (int u = 0; u < 16; ++u) acc[u] += xv * wrow[u];
  }
  __syncthreads();
  int row = rows0 + lane;
  float d = (row < NN) ? dis[row] : 0.f;
  #pragma unroll
  for (int u = 0; u < 16; ++u) xs[lane * 65 + cobase + u] = acc[u] * d;
  __syncthreads();
  for (int i = 0; i < 4; ++i) {
    int f = t + i * 256;
    int r = f >> 4, c4 = (f & 15) * 4;
    int orow = rows0 + r;
    if (orow < NN) {
      __half2 h0 = __floats2half2_rn(xs[r*65+c4+0], xs[r*65+c4+1]);
      __half2 h1 = __floats2half2_rn(xs[r*65+c4+2], xs[r*65+c4+3]);
      uint2 pk;
      pk.x = *reinterpret_cast<unsigned int*>(&h0);
      pk.y = *reinterpret_cast<unsigned int*>(&h1);
      *reinterpret_cast<uint2*>(dstH + (size_t)orow * 64 + c4) = pk;
    }
  }
}

// ---- aggregation v3: wave per node; lanes = 4 edges x 16 ch-quarters; fp16 T rows ----
// 2 groups (8 rows) in flight; meta prefetched one iteration ahead.
// wstride: 1 (dense plane) or 8 (wcsr8 fallback)
// mode 0: out = v ; mode 1: X1 = v + skipA ; mode 2: relu(v+skipA+skipX1) -> atomicMax pool
__global__ __launch_bounds__(256) void k_agg(const __half* __restrict__ T, const float* __restrict__ wj,
                                             const int* __restrict__ csrc, const int* __restrict__ cptr,
                                             const float* __restrict__ dis, float* __restrict__ out,
                                             const float* __restrict__ skipA, const float* __restrict__ skipX1,
                                             float* __restrict__ outX1, const int* __restrict__ batch,
                                             int* __restrict__ poolI, int wstride, int mode) {
  int t = threadIdx.x;
  int n = blockIdx.x * 4 + (t >> 6);
  if (n >= NN) return;
  int lane = t & 63;
  int e4 = lane >> 4;     // edge slot 0..3
  int cq = lane & 15;     // channel quarter 0..15
  int lo = cptr[n], hi = cptr[n + 1];

  // self loop (only edge-slot 0 keeps it)
  float4 tn = ld_half4(T + (size_t)n * 64 + cq * 4);
  float4 acc;
  acc.x = e4 == 0 ? tn.x : 0.f;
  acc.y = e4 == 0 ? tn.y : 0.f;
  acc.z = e4 == 0 ? tn.z : 0.f;
  acc.w = e4 == 0 ? tn.w : 0.f;

  int base = lo;
  int ka = base + e4;
  int kb = base + 4 + e4;
  bool va = ka < hi, vb = kb < hi;
  int   sa = va ? csrc[ka] : n;
  float wa = va ? wj[(size_t)ka * wstride] : 0.f;
  int   sb = vb ? csrc[kb] : n;
  float wb = vb ? wj[(size_t)kb * wstride] : 0.f;
  while (base < hi) {          // wave-uniform; consumes 8 edges/iter
    int csa = sa, csb = sb;
    float cwa = wa, cwb = wb;
    base += 8;
    ka = base + e4;
    kb = base + 4 + e4;
    va = ka < hi; vb = kb < hi;
    sa = va ? csrc[ka] : n;
    wa = va ? wj[(size_t)ka * wstride] : 0.f;
    sb = vb ? csrc[kb] : n;
    wb = vb ? wj[(size_t)kb * wstride] : 0.f;
    float4 qa = ld_half4(T + (size_t)csa * 64 + cq * 4);
    float4 qb = ld_half4(T + (size_t)csb * 64 + cq * 4);
    acc.x += cwa * qa.x + cwb * qb.x;
    acc.y += cwa * qa.y + cwb * qb.y;
    acc.z += cwa * qa.z + cwb * qb.z;
    acc.w += cwa * qa.w + cwb * qb.w;
  }

  // reduce over edge slots (lanes stride 16, then 32)
  acc.x += __shfl_xor(acc.x, 16); acc.y += __shfl_xor(acc.y, 16);
  acc.z += __shfl_xor(acc.z, 16); acc.w += __shfl_xor(acc.w, 16);
  acc.x += __shfl_xor(acc.x, 32); acc.y += __shfl_xor(acc.y, 32);
  acc.z += __shfl_xor(acc.z, 32); acc.w += __shfl_xor(acc.w, 32);

  if (e4 != 0) return;
  float d = dis[n];
  float4 v = make_float4(acc.x * d, acc.y * d, acc.z * d, acc.w * d);
  size_t ridx = (size_t)n * 16 + cq;
  if (mode == 1) {
    float4 a = reinterpret_cast<const float4*>(skipA)[ridx];
    float4 sv = make_float4(v.x + a.x, v.y + a.y, v.z + a.z, v.w + a.w);
    reinterpret_cast<float4*>(outX1)[ridx] = sv;
  } else if (mode == 2) {
    float4 a = reinterpret_cast<const float4*>(skipA)[ridx];
    float4 x1 = reinterpret_cast<const float4*>(skipX1)[ridx];
    float4 sv = make_float4(v.x + a.x + x1.x, v.y + a.y + x1.y, v.z + a.z + x1.z, v.w + a.w + x1.w);
    sv.x = sv.x > 0.f ? sv.x : 0.f;
    sv.y = sv.y > 0.f ? sv.y : 0.f;
    sv.z = sv.z > 0.f ? sv.z : 0.f;
    sv.w = sv.w > 0.f ? sv.w : 0.f;
    int g = batch[n];
    int* pb = poolI + (size_t)g * 64 + cq * 4;
    atomicMax(pb + 0, __float_as_int(sv.x));
    atomicMax(pb + 1, __float_as_int(sv.y));
    atomicMax(pb + 2, __float_as_int(sv.z));
    atomicMax(pb + 3, __float_as_int(sv.w));
  } else {
    reinterpret_cast<float4*>(out)[ridx] = v;
  }
}

__global__ __launch_bounds__(256) void k_cls(const float* __restrict__ pooled, const float* __restrict__ lw,
                                             const float* __restrict__ lb, float* __restrict__ out) {
  int id = blockIdx.x * 256 + threadIdx.x;
  if (id >= NG * NCLS) return;
  int g = id / NCLS, k = id % NCLS;
  float acc = lb[k];
  #pragma unroll 8
  for (int c = 0; c < 64; ++c) acc += pooled[g * 64 + c] * lw[k * 64 + c];
  out[id] = acc;
}

extern "C" void kernel_launch(void* const* d_in, const int* in_sizes, int n_in,
                              void* d_out, int out_size, void* d_ws, size_t ws_size,
                              hipStream_t stream) {
  (void)in_sizes; (void)n_in; (void)out_size;
  const float* x     = (const float*)d_in[0];
  const int*   ei    = (const int*)d_in[1];
  const int*   batch = (const int*)d_in[2];
  // d_in[3] = dropout (0) -- unused
  const float* ea    = (const float*)d_in[4];
  const float* c1_lw = (const float*)d_in[5];
  const float* c1_w1 = (const float*)d_in[6];
  const float* c1_b1 = (const float*)d_in[7];
  const float* c1_w2 = (const float*)d_in[8];
  const float* c1_b2 = (const float*)d_in[9];
  const float* h1_lw = (const float*)d_in[10];
  const float* h1_w1 = (const float*)d_in[11];
  const float* h1_b1 = (const float*)d_in[12];
  const float* h1_w2 = (const float*)d_in[13];
  const float* h1_b2 = (const float*)d_in[14];
  const float* h2_lw = (const float*)d_in[15];
  const float* h2_w1 = (const float*)d_in[16];
  const float* h2_b1 = (const float*)d_in[17];
  const float* h2_w2 = (const float*)d_in[18];
  const float* h2_b2 = (const float*)d_in[19];
  const float* lin_w = (const float*)d_in[20];
  const float* lin_b = (const float*)d_in[21];
  float* out = (float*)d_out;

  char* base = (char*)d_ws;
  size_t off = 0;
  auto alloc = [&](size_t bytes) -> size_t {
    size_t o = off;
    off = (off + bytes + 255) & ~(size_t)255;
    return o;
  };
  size_t o_wcsr8  = alloc((size_t)NE * 8 * 4);        // 25.6MB, CSR order, 8 floats/edge
  size_t o_csrc   = alloc((size_t)NE * 4);
  size_t o_pos    = alloc((size_t)NE * 4);
  size_t o_cptr   = alloc((size_t)(NN + 1) * 4);
  size_t o_excl   = alloc((size_t)NN * 4);
  size_t o_bsum   = alloc((size_t)64 * 4);
  size_t o_boff   = alloc((size_t)64 * 4);
  size_t o_cnt    = alloc((size_t)NN * 4);            // zeroed region starts here (cnt -> cursor)
  size_t o_accum  = alloc((size_t)6 * 128 * 4);       // zeroed region ends after this
  size_t o_dis    = alloc((size_t)NCONV * NN * 4);
  size_t o_lwt    = alloc((size_t)NCONV * 4096 * 4);
  size_t o_T      = alloc((size_t)NN * 64 * 2);       // fp16 T: 6.4MB
  size_t o_A      = alloc((size_t)NN * 64 * 4);
  size_t o_B      = alloc((size_t)NN * 64 * 4);
  size_t o_X1     = alloc((size_t)NN * 64 * 4);
  size_t o_pool   = alloc((size_t)NG * 64 * 4);
  size_t o_wpl    = alloc((size_t)NCONV * NE * 4);    // 22.4MB dense planes -- LAST, gated on ws_size
  bool use_planes = (off <= ws_size);

  float* wcsr8  = (float*)(base + o_wcsr8);
  int*   csrc   = (int*)(base + o_csrc);
  int*   pos    = (int*)(base + o_pos);
  int*   cptr   = (int*)(base + o_cptr);
  int*   excl   = (int*)(base + o_excl);
  int*   bsum   = (int*)(base + o_bsum);
  int*   boff   = (int*)(base + o_boff);
  int*   cnt    = (int*)(base + o_cnt);   // doubles as cursor after scanC
  float* accum  = (float*)(base + o_accum);
  float* dis    = (float*)(base + o_dis);
  float* lwt    = (float*)(base + o_lwt);
  __half* T     = (__half*)(base + o_T);
  float* A      = (float*)(base + o_A);
  float* B      = (float*)(base + o_B);
  float* X1     = (float*)(base + o_X1);
  float* pooled = (float*)(base + o_pool);
  float* wpl    = (float*)(base + o_wpl);

  // zero: cnt + accum (contiguous), and pooled (atomicMax target; relu values >= 0)
  hipMemsetAsync(base + o_cnt, 0, o_dis - o_cnt, stream);
  hipMemsetAsync(base + o_pool, 0, (size_t)NG * 64 * 4, stream);

  const int* erow = ei;
  const int* ecol = ei + NE;

  k_hist<<<(NE + 255) / 256, 256, 0, stream>>>(ecol, cnt);
  k_scanA<<<SCAN_B, 1024, 0, stream>>>(cnt, excl, bsum);
  k_scanB<<<1, 64, 0, stream>>>(bsum, boff);
  k_scanC<<<SCAN_B, 1024, 0, stream>>>(excl, boff, cptr, cnt);
  k_scatter<<<(NE + 255) / 256, 256, 0, stream>>>(erow, ecol, cnt, csrc, pos);

  MlpAll mw;
  mw.p[0] = {c1_w1, c1_b1, c1_w2, c1_b2};
  for (int i = 0; i < 3; ++i) {
    mw.p[1 + i] = {h1_w1 + i * 256, h1_b1 + i * 16, h1_w2 + i * 16, h1_b2 + i};
    mw.p[4 + i] = {h2_w1 + i * 256, h2_b1 + i * 16, h2_w2 + i * 16, h2_b2 + i};
  }
  k_mlp<<<(NE / 4 + 255) / 256, 256, 0, stream>>>(pos, ea, wcsr8, mw);
  if (use_planes) k_repack<<<(NE + 255) / 256, 256, 0, stream>>>(wcsr8, wpl);
  k_deg<<<(NN + 255) / 256, 256, 0, stream>>>(wcsr8, cptr, dis);
  k_lwt<<<(NCONV * 4096) / 256, 256, 0, stream>>>(c1_lw, h1_lw, h2_lw, lwt);

  const int GB = (NN + 63) / 64;  // 782
  const int AB = (NN + 3) / 4;    // 12500
  auto wbase = [&](int j) -> const float* {
    return use_planes ? (wpl + (size_t)j * NE) : (wcsr8 + j);
  };
  const int WS = use_planes ? 1 : 8;

  // conv1 -> A (= x0)
  k_gemm<<<GB, 256, 0, stream>>>(x, lwt, nullptr, dis, T, 0);
  k_agg<<<AB, 256, 0, stream>>>(T, wbase(0), csrc, cptr, dis, A,
                                nullptr, nullptr, nullptr, nullptr, nullptr, WS, 0);

  // hidden loop 1: x = conv(relu(BN(x))); after i==2 fuse x1 = x + x0 -> X1 only
  for (int i = 0; i < 3; ++i) {
    const float* src = (i == 0) ? A : B;
    k_bnstat<<<256, 256, 0, stream>>>(src, accum + i * 128);
    k_gemm<<<GB, 256, 0, stream>>>(src, lwt + (1 + i) * 4096, accum + i * 128,
                                   dis + (size_t)(1 + i) * NN, T, 1);
    int mode = (i == 2) ? 1 : 0;
    k_agg<<<AB, 256, 0, stream>>>(T, wbase(1 + i), csrc, cptr,
                                  dis + (size_t)(1 + i) * NN, B, A, nullptr, X1,
                                  nullptr, nullptr, WS, mode);
  }
  // hidden loop 2 (input = X1); after i==2 fuse x2=relu(x+x0+x1) + max-pool via atomics
  for (int i = 0; i < 3; ++i) {
    const float* src = (i == 0) ? X1 : B;
    k_bnstat<<<256, 256, 0, stream>>>(src, accum + (3 + i) * 128);
    k_gemm<<<GB, 256, 0, stream>>>(src, lwt + (4 + i) * 4096, accum + (3 + i) * 128,
                                   dis + (size_t)(4 + i) * NN, T, 1);
    int mode = (i == 2) ? 2 : 0;
    k_agg<<<AB, 256, 0, stream>>>(T, wbase(4 + i), csrc, cptr,
                                  dis + (size_t)(4 + i) * NN, B, A, X1, nullptr,
                                  batch, (int*)pooled, WS, mode);
  }

  k_cls<<<(NG * NCLS + 255) / 256, 256, 0, stream>>>(pooled, lin_w, lin_b, out);
}